// Round 9
// baseline (895.055 us; speedup 1.0000x reference)
//
#include <hip/hip_runtime.h>
#include <hip/hip_bf16.h>

#define ENC_DIM 2048
#define DEC_DIM 512
#define ATT_DIM 512
#define BATCH   256
#define NPIX    196
#define MROWS   (BATCH * NPIX)          // 50176 = 392 * 128
#define KT_N    64                      // K-steps of 32

typedef __attribute__((ext_vector_type(8)))  short short8;
typedef __attribute__((ext_vector_type(4)))  float f32x4;

typedef const __attribute__((address_space(1))) unsigned int gu32;
typedef __attribute__((address_space(3))) unsigned int lu32;

#define FENCE asm volatile("" ::: "memory")   // pin vmem issue order (no inst)

__device__ __forceinline__ short f2bf(float x) {
    unsigned u = __builtin_bit_cast(unsigned, x);
    unsigned r = (u + 0x7FFFu + ((u >> 16) & 1u)) >> 16;
    return (short)r;
}
__device__ __forceinline__ unsigned pkbf(float a, float b) {
    unsigned r;
    asm("v_cvt_pk_bf16_f32 %0, %1, %2" : "=v"(r) : "v"(a), "v"(b));
    return r;
}

// ---------------------------------------------------------------------------
// prep: blocks [0,256)   -> att2pb[b][a] = b_enc[a] + b_dec[a] + h[b]·W_dec[:,a]
//       blocks [256,768) -> pack W_enc into bf16 16x16x32 B-fragment order:
//         16B-chunk c = nt*4096 + kt*64 + l ;
//         elem j = W_enc[kt*32+((l>>4)&3)*8+j][nt*16+(l&15)]
// ---------------------------------------------------------------------------
__global__ __launch_bounds__(256) void bahdanau_prep(
    const float* __restrict__ dec_h, const float* __restrict__ W_enc,
    const float* __restrict__ b_enc, const float* __restrict__ W_dec,
    const float* __restrict__ b_dec,
    float* __restrict__ att2pb, short* __restrict__ Wpack)
{
    int blk = blockIdx.x;
    if (blk < BATCH) {
        __shared__ float hs[DEC_DIM];
        int b = blk;
        for (int i = threadIdx.x; i < DEC_DIM; i += 256) hs[i] = dec_h[b * DEC_DIM + i];
        __syncthreads();
        for (int a = threadIdx.x; a < ATT_DIM; a += 256) {
            float s = 0.f;
            #pragma unroll 8
            for (int d = 0; d < DEC_DIM; ++d) s += hs[d] * W_dec[d * ATT_DIM + a];
            att2pb[b * ATT_DIM + a] = s + b_dec[a] + b_enc[a];
        }
    } else {
        int c  = (blk - BATCH) * 256 + threadIdx.x;   // 0 .. 131071
        int l  = c & 63;
        int kt = (c >> 6) & 63;
        int nt = c >> 12;
        int n     = nt * 16 + (l & 15);
        int kbase = kt * 32 + ((l >> 4) & 3) * 8;
        short8 v;
        #pragma unroll
        for (int j = 0; j < 8; ++j) v[j] = f2bf(W_enc[(kbase + j) * ATT_DIM + n]);
        *reinterpret_cast<short8*>(Wpack + (size_t)c * 8) = v;
    }
}

// ---------------------------------------------------------------------------
// gemm: 256 thr, 4 waves (2 wm x 2 wn); block tile 128x128; wave 64x64 = 4x4
// frags of 16x16x32 bf16. 64 K-steps of 32.
// 3-step-deep RACE-FREE counted pipeline:
//   A: global->VGPR (2 reg sets) -> cvt_pk -> ds_write, 2 LDS bufs.
//      A(t+3) issued at step t (2.3 steps to land).
//   B: global_load_lds from packed Wpack, 4 LDS bufs. B(t+3) issued at
//      step t (3 steps to land).
//   Step: vmcnt(8) [my B(t),A(t+1) landed] -> lgkm(0) -> s_barrier
//   [=> ALL waves' B(t) landed: race-free] -> WRITEA(t+1) -> LOADA(t+3)
//   -> STAGEB(t+3) -> COMPUTE(t). vmcnt never drains mid-loop.
// LDS 49KB -> 3 blocks/CU. Epilogue: relu(att1+att2)·w_full -> spart.
// ---------------------------------------------------------------------------
__global__ __launch_bounds__(256, 3) void bahdanau_gemm(
    const float* __restrict__ enc, const float* __restrict__ w_full,
    const float* __restrict__ att2pb, const short* __restrict__ Wpack,
    float* __restrict__ spart)
{
    __shared__ __align__(16) short Abuf[2][4096];   // 2 x 8 KB
    __shared__ __align__(16) short Bbuf[4][4096];   // 4 x 8 KB
    __shared__ float redm[2][128];

    const int wg = blockIdx.x;
    const int g  = (wg & 7) * 196 + (wg >> 3);      // bijective XCD swizzle
    const int mt = g >> 2;
    const int nc = g & 3;

    const int tid  = threadIdx.x;
    const int lane = tid & 63;
    const int wid  = tid >> 6;
    const int wm   = wid >> 1;
    const int wn   = wid & 1;

    // A: thread -> row = tid>>1 (of 128), 16 floats at k = (tid&1)*16
    const float* aSrc = enc + (size_t)(mt * 128 + (tid >> 1)) * ENC_DIM + (tid & 1) * 16;
    const int adst = (((tid >> 5) * 64) + ((tid & 1) * 32) + ((tid >> 1) & 15)) * 8;

    // B: dest chunks d = tid, tid+256; src 16B-chunk (nc*8 + (d>>6))*4096 + (d&63)
    const short* bs0 = Wpack + ((size_t)(nc * 8 + (tid >> 6)) * 4096 + (tid & 63)) * 8;
    const short* bs1 = bs0 + (size_t)4 * 4096 * 8;

    f32x4 acc[4][4];
    #pragma unroll
    for (int a = 0; a < 4; ++a)
        #pragma unroll
        for (int c = 0; c < 4; ++c)
            #pragma unroll
            for (int r = 0; r < 4; ++r) acc[a][c][r] = 0.f;

    float4 ar[2][4];                                // 2 in-flight A reg sets

    auto LOADA = [&](int t, int s) {
        const float4* p = reinterpret_cast<const float4*>(aSrc + t * 32);
        ar[s][0] = p[0]; ar[s][1] = p[1]; ar[s][2] = p[2]; ar[s][3] = p[3];
    };
    auto WRITEA = [&](short* buf, int s) {
        union { short8 v; unsigned u[4]; } f0, f1;
        f0.u[0] = pkbf(ar[s][0].x, ar[s][0].y); f0.u[1] = pkbf(ar[s][0].z, ar[s][0].w);
        f0.u[2] = pkbf(ar[s][1].x, ar[s][1].y); f0.u[3] = pkbf(ar[s][1].z, ar[s][1].w);
        f1.u[0] = pkbf(ar[s][2].x, ar[s][2].y); f1.u[1] = pkbf(ar[s][2].z, ar[s][2].w);
        f1.u[2] = pkbf(ar[s][3].x, ar[s][3].y); f1.u[3] = pkbf(ar[s][3].z, ar[s][3].w);
        *reinterpret_cast<short8*>(buf + adst)       = f0.v;
        *reinterpret_cast<short8*>(buf + adst + 128) = f1.v;
    };
    auto STAGEB = [&](short* buf, int t) {
        __builtin_amdgcn_global_load_lds((gu32*)(bs0 + (size_t)t * 512),
                                         (lu32*)(buf + tid * 8), 16, 0, 0);
        __builtin_amdgcn_global_load_lds((gu32*)(bs1 + (size_t)t * 512),
                                         (lu32*)(buf + (tid + 256) * 8), 16, 0, 0);
    };
    auto COMPUTE = [&](const short* Ab, const short* Bb) {
        short8 af[4], bf[4];
        #pragma unroll
        for (int rt = 0; rt < 4; ++rt)
            af[rt] = *reinterpret_cast<const short8*>(Ab + ((wm * 4 + rt) * 64 + lane) * 8);
        #pragma unroll
        for (int ct = 0; ct < 4; ++ct)
            bf[ct] = *reinterpret_cast<const short8*>(Bb + ((wn * 4 + ct) * 64 + lane) * 8);
        #pragma unroll
        for (int rt = 0; rt < 4; ++rt)
            #pragma unroll
            for (int ct = 0; ct < 4; ++ct)
                acc[rt][ct] = __builtin_amdgcn_mfma_f32_16x16x32_bf16(af[rt], bf[ct], acc[rt][ct], 0, 0, 0);
    };

    // ---- prologue: establish stream [A0,B0,A1,B1] -> gate A0 -> [A2,B2]
    LOADA(0, 0);            FENCE;
    STAGEB(&Bbuf[0][0], 0); FENCE;
    LOADA(1, 1);            FENCE;
    STAGEB(&Bbuf[1][0], 1); FENCE;
    asm volatile("s_waitcnt vmcnt(8)" ::: "memory");    // A0 landed
    WRITEA(&Abuf[0][0], 0); FENCE;
    LOADA(2, 0);            FENCE;
    STAGEB(&Bbuf[2][0], 2); FENCE;
    asm volatile("s_waitcnt lgkmcnt(0)" ::: "memory");
    __builtin_amdgcn_s_barrier();
    __builtin_amdgcn_sched_barrier(0);

    // ---- main loop t = 0..61 (uniform gate vmcnt(8)); peel 62, 63
    for (int t = 0; t < KT_N - 2; ++t) {
        asm volatile("s_waitcnt vmcnt(8)" ::: "memory");   // my B(t), A(t+1) landed
        asm volatile("s_waitcnt lgkmcnt(0)" ::: "memory");
        __builtin_amdgcn_s_barrier();                      // ALL waves' B(t) landed
        __builtin_amdgcn_sched_barrier(0);
        const int sp = (t + 1) & 1;
        WRITEA(&Abuf[sp][0], sp);                          // A(t+1) -> LDS
        FENCE;
        if (t < KT_N - 3) {
            LOADA(t + 3, sp);                              // A(t+3) in flight
            FENCE;
            STAGEB(&Bbuf[(t + 3) & 3][0], t + 3);          // B(t+3) in flight
            FENCE;
        }
        COMPUTE(&Abuf[t & 1][0], &Bbuf[t & 3][0]);
    }
    // t = 62: outstanding B62,A63,B63 -> need A63,B62 -> leave B63 (2)
    asm volatile("s_waitcnt vmcnt(2)" ::: "memory");
    asm volatile("s_waitcnt lgkmcnt(0)" ::: "memory");
    __builtin_amdgcn_s_barrier();
    __builtin_amdgcn_sched_barrier(0);
    WRITEA(&Abuf[1][0], 1);
    COMPUTE(&Abuf[0][0], &Bbuf[62 & 3][0]);
    // t = 63
    asm volatile("s_waitcnt vmcnt(0)" ::: "memory");
    asm volatile("s_waitcnt lgkmcnt(0)" ::: "memory");
    __builtin_amdgcn_s_barrier();
    __builtin_amdgcn_sched_barrier(0);
    COMPUTE(&Abuf[1][0], &Bbuf[63 & 3][0]);

    // ---- epilogue: relu(att1 + att2)·w_full -> per-row partials over 64 cols
    float srow[16];
    #pragma unroll
    for (int i = 0; i < 16; ++i) srow[i] = 0.f;
    #pragma unroll
    for (int ct = 0; ct < 4; ++ct) {
        int col  = nc * 128 + wn * 64 + ct * 16 + (lane & 15);
        float wf = w_full[col];
        #pragma unroll
        for (int rt = 0; rt < 4; ++rt) {
            #pragma unroll
            for (int r = 0; r < 4; ++r) {
                unsigned grow = mt * 128 + wm * 64 + rt * 16 + (lane >> 4) * 4 + r;
                unsigned bb   = grow / NPIX;
                float v = acc[rt][ct][r] + att2pb[bb * ATT_DIM + col];
                srow[rt * 4 + r] += fmaxf(v, 0.f) * wf;
            }
        }
    }
    #pragma unroll
    for (int i = 0; i < 16; ++i) {
        float v = srow[i];
        v += __shfl_xor(v, 1);
        v += __shfl_xor(v, 2);
        v += __shfl_xor(v, 4);
        v += __shfl_xor(v, 8);
        srow[i] = v;
    }
    if ((lane & 15) == 0) {
        #pragma unroll
        for (int rt = 0; rt < 4; ++rt)
            #pragma unroll
            for (int r = 0; r < 4; ++r)
                redm[wn][wm * 64 + rt * 16 + (lane >> 4) * 4 + r] = srow[rt * 4 + r];
    }
    __syncthreads();
    if (tid < 128)
        spart[(size_t)nc * MROWS + mt * 128 + tid] = redm[0][tid] + redm[1][tid];
}

// ---------------------------------------------------------------------------
// ctx: grid 256. Sum 4 nc score partials, softmax (b_full invariant),
// write alpha, stream context: thread -> one float4 column, 196-pixel loop.
// ---------------------------------------------------------------------------
__global__ __launch_bounds__(512) void bahdanau_ctx(
    const float* __restrict__ enc, const float* __restrict__ spart,
    float* __restrict__ out_ctx, float* __restrict__ out_alpha)
{
    __shared__ float al[256];
    __shared__ float msum[2];
    const int b    = blockIdx.x;
    const int tid  = threadIdx.x;
    const int lane = tid & 63;
    const int wid  = tid >> 6;

    if (tid < NPIX) {
        int row = b * NPIX + tid;
        al[tid] = spart[row] + spart[MROWS + row] + spart[2 * MROWS + row] + spart[3 * MROWS + row];
    } else if (tid < 256) {
        al[tid] = -3.4e38f;
    }
    __syncthreads();

    if (wid == 0) {
        float s0 = al[lane], s1 = al[lane + 64], s2 = al[lane + 128], s3 = al[lane + 192];
        float m = fmaxf(fmaxf(s0, s1), fmaxf(s2, s3));
        #pragma unroll
        for (int d = 1; d <= 32; d <<= 1) m = fmaxf(m, __shfl_xor(m, d));
        float e = __expf(s0 - m) + __expf(s1 - m) + __expf(s2 - m) + __expf(s3 - m);
        #pragma unroll
        for (int d = 1; d <= 32; d <<= 1) e += __shfl_xor(e, d);
        if (lane == 0) { msum[0] = m; msum[1] = e; }
    }
    __syncthreads();
    float m    = msum[0];
    float rinv = 1.f / msum[1];
    if (tid < NPIX) {
        float a = __expf(al[tid] - m) * rinv;
        al[tid] = a;
        out_alpha[b * NPIX + tid] = a;
    }
    __syncthreads();

    float4 c4 = {0.f, 0.f, 0.f, 0.f};
    const float4* enc4 = reinterpret_cast<const float4*>(enc + (size_t)b * NPIX * ENC_DIM);
    #pragma unroll 4
    for (int p = 0; p < NPIX; ++p) {
        float a  = al[p];
        float4 v = enc4[(size_t)p * (ENC_DIM / 4) + tid];
        c4.x += a * v.x; c4.y += a * v.y; c4.z += a * v.z; c4.w += a * v.w;
    }
    reinterpret_cast<float4*>(out_ctx)[(size_t)b * (ENC_DIM / 4) + tid] = c4;
}

extern "C" void kernel_launch(void* const* d_in, const int* in_sizes, int n_in,
                              void* d_out, int out_size, void* d_ws, size_t ws_size,
                              hipStream_t stream) {
    const float* enc    = (const float*)d_in[0];
    const float* dech   = (const float*)d_in[1];
    const float* W_enc  = (const float*)d_in[2];
    const float* b_enc  = (const float*)d_in[3];
    const float* W_dec  = (const float*)d_in[4];
    const float* b_dec  = (const float*)d_in[5];
    const float* w_full = (const float*)d_in[6];
    // d_in[7] = b_full: softmax-invariant, unused.

    float* att2pb = (float*)d_ws;                              // 512 KiB
    short* Wpack  = (short*)((char*)d_ws + 512 * 1024);        // 2 MiB
    float* spart  = (float*)((char*)d_ws + 2560 * 1024);       // 4*50176*4 = 784 KiB

    float* out_ctx   = (float*)d_out;
    float* out_alpha = out_ctx + (size_t)BATCH * ENC_DIM;

    bahdanau_prep<<<768, 256, 0, stream>>>(dech, W_enc, b_enc, W_dec, b_dec, att2pb, Wpack);
    bahdanau_gemm<<<1568, 256, 0, stream>>>(enc, w_full, att2pb, Wpack, spart);
    bahdanau_ctx<<<BATCH, 512, 0, stream>>>(enc, spart, out_ctx, out_alpha);
}